// Round 4
// baseline (197.466 us; speedup 1.0000x reference)
//
#include <hip/hip_runtime.h>

typedef __attribute__((ext_vector_type(4))) float f32x4;
typedef __attribute__((ext_vector_type(8))) short s16x8;
typedef __attribute__((ext_vector_type(4))) short s16x4;
typedef __bf16 bf16x4 __attribute__((ext_vector_type(4)));

#define B_   96
#define NQ   35
#define LP   180
#define H_   768
#define D_   128
#define NEGF (-1e30f)

#define NROWS 37920
#define QROWS 3360
#define PROWS 17280

__device__ __forceinline__ unsigned short f2bf(float f) {
    return __builtin_bit_cast(unsigned short, (__bf16)f);
}

__device__ __forceinline__ s16x4 cvt_bf4(f32x4 v) {
    return __builtin_bit_cast(s16x4, __builtin_convertvector(v, bf16x4));
}

__device__ __forceinline__ s16x8 pack_bf16(f32x4 v0, f32x4 v1) {
    bf16x4 h0 = __builtin_convertvector(v0, bf16x4);
    bf16x4 h1 = __builtin_convertvector(v1, bf16x4);
    s16x4 a = __builtin_bit_cast(s16x4, h0), b = __builtin_bit_cast(s16x4, h1);
    return __builtin_shufflevector(a, b, 0, 1, 2, 3, 4, 5, 6, 7);
}

// async global->LDS, 16 B per lane; lds dest must be wave-uniform (HW adds lane*16)
__device__ __forceinline__ void glds16(const void* g, void* l) {
    __builtin_amdgcn_global_load_lds(
        (const __attribute__((address_space(1))) unsigned int*)g,
        (__attribute__((address_space(3))) unsigned int*)l,
        16, 0, 0);
}

// 16B global load via inline asm (SGPR base + 32-bit VGPR offset): the compiler inserts
// NO waitcnt for asm defs, so these participate in the hand-counted vmcnt schedule.
__device__ __forceinline__ s16x8 ldg16(const unsigned short* sbase, unsigned int voff) {
    s16x8 r;
    asm volatile("global_load_dwordx4 %0, %1, %2"
                 : "=v"(r) : "v"(voff), "s"(sbase));
    return r;
}

#define WAITV(N) do {                                                 \
    asm volatile("s_waitcnt vmcnt(" #N ")" ::: "memory");             \
    __builtin_amdgcn_sched_barrier(0);                                \
} while (0)

#define BAR() do {                                                    \
    __builtin_amdgcn_sched_barrier(0);                                \
    __builtin_amdgcn_s_barrier();                                     \
} while (0)

// ---------------- prep: wt_build (blocks 0-47) + ssq zero (48-191) + mask detect (192) ----
__global__ __launch_bounds__(256) void prep_k(
    const float* __restrict__ W, unsigned short* __restrict__ wthi,
    const unsigned int* __restrict__ pmask_w, unsigned int* __restrict__ ctrl,
    float* __restrict__ ssq) {
    __shared__ unsigned int rr[256];
    int b = blockIdx.x, t = threadIdx.x;
    if (b < 48) {
        int tid = b * 256 + t;
        int nt = tid / (24 * 64);
        int r = tid - nt * 24 * 64;
        int ks = r / 64, lane = r - ks * 64;
        int m = lane & 15, quad = lane >> 4;
        unsigned short* o = wthi + (size_t)tid * 8;
#pragma unroll
        for (int j = 0; j < 8; j++) {
            int k = ks * 32 + quad * 8 + j;
            o[j] = f2bf(W[(size_t)k * D_ + nt * 16 + m]);
        }
    } else if (b < 192) {
        ssq[(b - 48) * 256 + t] = 0.f;       // 144*256 = 36864 exactly
    } else {
        unsigned int f1 = 0, f3 = 0, f4 = 0;
        for (int w = t; w < 4320; w += 256) {
            unsigned int v = pmask_w[w];
            f1 |= v & 0x0000ff00u;                 // byte %4==1 -> 1-byte layout
            f3 |= v & 0xff000000u;                 // byte %4==3 -> float32
            if (w & 1) f4 |= v & 0x000000ffu;      // byte %8==4 -> int32
        }
        rr[t] = f1; __syncthreads();
        for (int s2 = 128; s2; s2 >>= 1) { if (t < s2) rr[t] |= rr[t + s2]; __syncthreads(); }
        if (!t) ctrl[0] = rr[0];
        __syncthreads();
        rr[t] = f3; __syncthreads();
        for (int s2 = 128; s2; s2 >>= 1) { if (t < s2) rr[t] |= rr[t + s2]; __syncthreads(); }
        if (!t) ctrl[1] = rr[0];
        __syncthreads();
        rr[t] = f4; __syncthreads();
        for (int s2 = 128; s2; s2 >>= 1) { if (t < s2) rr[t] |= rr[t + s2]; __syncthreads(); }
        if (!t) ctrl[2] = rr[0];
    }
}

// ---------------- proj v7: glds 4-ring (f32 A) + counted vmcnt + B reg-prefetch ---------
// R3 analysis: proj is CONCURRENCY-limited (Little's law): ~0.4 KB in flight per CU vs
// ~15 KB needed -> A+B served at 2.4 TB/s; plus a ~250cy L2 stall per iter on B frags
// loaded at their use point. v7: (a) A staged RAW f32 by global_load_lds into a 4-deep
// LDS ring (1 KB in flight per glds, zero VGPR) with hand-counted vmcnt(8) -- 3 steps
// of A + 1 group of B always in flight, never drained to 0 in steady state; (b) B
// fragments prefetched 1 iter ahead into regs via asm loads (compiler adds no waits for
// asm defs -> they obey the counted schedule); (c) bf16 convert at consume time
// (pack_bf16); no ds_writes at all -> raw s_barrier only, 12 barriers (was 24).
// Bank conflicts: glds writes LDS linearly, so the READ swizzle (chunk c = cg^2*(row&7))
// is applied by inverse-permuting the per-lane GLOBAL source address (rule #21). Lane's
// two 16B chunks stay adjacent and in order (both XOR terms even). Arithmetic is
// bit-identical to v3/v6 (same values, same MFMA order, same epilogue).
#define STAGE(S) do {                                                                     \
    float* ldw = ld0 + ((S)&3) * 2048;                                                    \
    glds16(gq0 + (S) * 64, ldw);                                                          \
    glds16(gq1 + (S) * 64, ldw + 256);                                                    \
} while (0)

#define LDB(p0, p1, p2, p3, S1) do {                                                      \
    unsigned int k0 = (unsigned int)((S1) * 2048u);                                       \
    p0 = ldg16(wthi, ob0 + k0);                                                           \
    p1 = ldg16(wthi, ob1 + k0);                                                           \
    p2 = ldg16(wthi, ob0 + k0 + 1024u);                                                   \
    p3 = ldg16(wthi, ob1 + k0 + 1024u);                                                   \
} while (0)

#define ACOMP(S, B0, B1, B2, B3) do {                                                     \
    const float* bb = &lds[((S)&3) * 2048];                                               \
    f32x4 l, h;                                                                           \
    l = *(const f32x4*)(bb + rb0 + cA0); h = *(const f32x4*)(bb + rb0 + cA0 + 4);         \
    s16x8 a00 = pack_bf16(l, h);                                                          \
    l = *(const f32x4*)(bb + rb1 + cA0); h = *(const f32x4*)(bb + rb1 + cA0 + 4);         \
    s16x8 a10 = pack_bf16(l, h);                                                          \
    l = *(const f32x4*)(bb + rb0 + cA1); h = *(const f32x4*)(bb + rb0 + cA1 + 4);         \
    s16x8 a01 = pack_bf16(l, h);                                                          \
    l = *(const f32x4*)(bb + rb1 + cA1); h = *(const f32x4*)(bb + rb1 + cA1 + 4);         \
    s16x8 a11 = pack_bf16(l, h);                                                          \
    acc[0][0] = __builtin_amdgcn_mfma_f32_16x16x32_bf16(a00, B0, acc[0][0], 0, 0, 0);     \
    acc[0][1] = __builtin_amdgcn_mfma_f32_16x16x32_bf16(a00, B1, acc[0][1], 0, 0, 0);     \
    acc[1][0] = __builtin_amdgcn_mfma_f32_16x16x32_bf16(a10, B0, acc[1][0], 0, 0, 0);     \
    acc[1][1] = __builtin_amdgcn_mfma_f32_16x16x32_bf16(a10, B1, acc[1][1], 0, 0, 0);     \
    acc[0][0] = __builtin_amdgcn_mfma_f32_16x16x32_bf16(a01, B2, acc[0][0], 0, 0, 0);     \
    acc[0][1] = __builtin_amdgcn_mfma_f32_16x16x32_bf16(a01, B3, acc[0][1], 0, 0, 0);     \
    acc[1][0] = __builtin_amdgcn_mfma_f32_16x16x32_bf16(a11, B2, acc[1][0], 0, 0, 0);     \
    acc[1][1] = __builtin_amdgcn_mfma_f32_16x16x32_bf16(a11, B3, acc[1][1], 0, 0, 0);     \
} while (0)

__global__ __launch_bounds__(256, 4) void proj_k(
    const float* __restrict__ qh, const float* __restrict__ ph, const float* __restrict__ nh,
    const unsigned short* __restrict__ wthi, const float* __restrict__ bias,
    float* __restrict__ x, float* __restrict__ ssq,
    const void* __restrict__ pm, const void* __restrict__ nm,
    const unsigned int* __restrict__ ctrl, unsigned char* __restrict__ maskc) {
    __shared__ float lds[8192];                      // 4-ring x 32 rows x 64 f32 = 32 KB
    int b = blockIdx.x;
    if (b >= 1185) {                                 // ---- mask canon: 135 blocks exact ----
        int i = (b - 1185) * 256 + threadIdx.x;      // < 34560
        const void* src = (i < B_ * LP) ? pm : nm;
        int j = (i < B_ * LP) ? i : i - B_ * LP;
        unsigned int c1 = ctrl[0], c3 = ctrl[1], c4 = ctrl[2];
        bool bit;
        if (c1 > 0)       bit = ((const unsigned char*)src)[j] != 0;
        else if (c3 > 0)  bit = ((const float*)src)[j] != 0.0f;
        else if (c4 > 0)  bit = ((const int*)src)[j] != 0;
        else              bit = ((const long long*)src)[j] != 0;
        maskc[i] = bit ? 1 : 0;
        return;
    }
    int t = threadIdx.x;
    int wave = t >> 6, lane = t & 63;
    const float* src; int row0l; int growbase;
    if (b < 105)      { src = qh; row0l = b * 32;         growbase = row0l; }
    else if (b < 645) { src = ph; row0l = (b - 105) * 32; growbase = QROWS + row0l; }
    else              { src = nh; row0l = (b - 645) * 32; growbase = QROWS + PROWS + row0l; }
    int m = lane & 15, quad = lane >> 4;

    // staging: wave w covers rows [8w, 8w+8): glds g in {0,1} covers 4 rows each.
    // lane's global source chunk is inverse-swizzled: cg = (lane&15) ^ 2*(row&7).
    int r0 = wave * 8 + (lane >> 4);
    int r1 = r0 + 4;
    int cg0 = (lane & 15) ^ (2 * (r0 & 7));
    int cg1 = (lane & 15) ^ (2 * (r1 & 7));
    const float* gq0 = src + (size_t)(row0l + r0) * H_ + cg0 * 4;
    const float* gq1 = src + (size_t)(row0l + r1) * H_ + cg1 * 4;
    float* ld0 = &lds[wave * 512];                   // wave's linear dest (+ ring offset)

    // B fragment byte offsets into wthi (advance 2048 B per k-step)
    int nt0 = wave * 2, nt1 = wave * 2 + 1;
    unsigned int ob0 = (unsigned int)(((nt0 * 24) * 64 + lane) * 16);
    unsigned int ob1 = (unsigned int)(((nt1 * 24) * 64 + lane) * 16);

    // read-side swizzled LDS addresses (float units)
    int swz = 2 * (m & 7);
    int rb0 = m * 64, rb1 = (m + 16) * 64;
    int cA0 = ((quad * 2) ^ swz) * 4;
    int cA1 = ((8 + quad * 2) ^ swz) * 4;

    f32x4 acc[2][2];
#pragma unroll
    for (int mt = 0; mt < 2; mt++)
#pragma unroll
        for (int ntl = 0; ntl < 2; ntl++) acc[mt][ntl] = (f32x4){0.f, 0.f, 0.f, 0.f};

    s16x8 bA0, bA1, bA2, bA3, bB0, bB1, bB2, bB3;

    // prologue: [glds(0), glds(1), B(0), glds(2)] in flight; drain glds(0) only
    STAGE(0);
    STAGE(1);
    LDB(bA0, bA1, bA2, bA3, 0);
    STAGE(2);
    WAITV(8);

    // steady iters: BAR; prefetch B(s+1); stage glds(s+3); vmcnt(8) drains {glds(s+1),B(s)}
    BAR(); LDB(bB0, bB1, bB2, bB3, 1);  STAGE(3);  WAITV(8); ACOMP(0,  bA0, bA1, bA2, bA3);
    BAR(); LDB(bA0, bA1, bA2, bA3, 2);  STAGE(4);  WAITV(8); ACOMP(1,  bB0, bB1, bB2, bB3);
    BAR(); LDB(bB0, bB1, bB2, bB3, 3);  STAGE(5);  WAITV(8); ACOMP(2,  bA0, bA1, bA2, bA3);
    BAR(); LDB(bA0, bA1, bA2, bA3, 4);  STAGE(6);  WAITV(8); ACOMP(3,  bB0, bB1, bB2, bB3);
    BAR(); LDB(bB0, bB1, bB2, bB3, 5);  STAGE(7);  WAITV(8); ACOMP(4,  bA0, bA1, bA2, bA3);
    BAR(); LDB(bA0, bA1, bA2, bA3, 6);  STAGE(8);  WAITV(8); ACOMP(5,  bB0, bB1, bB2, bB3);
    BAR(); LDB(bB0, bB1, bB2, bB3, 7);  STAGE(9);  WAITV(8); ACOMP(6,  bA0, bA1, bA2, bA3);
    BAR(); LDB(bA0, bA1, bA2, bA3, 8);  STAGE(10); WAITV(8); ACOMP(7,  bB0, bB1, bB2, bB3);
    BAR(); LDB(bB0, bB1, bB2, bB3, 9);  STAGE(11); WAITV(8); ACOMP(8,  bA0, bA1, bA2, bA3);
    // tail: no more staging; counted drains shrink 6 -> 4 -> 0
    BAR(); LDB(bA0, bA1, bA2, bA3, 10);            WAITV(6); ACOMP(9,  bB0, bB1, bB2, bB3);
    BAR(); LDB(bB0, bB1, bB2, bB3, 11);            WAITV(4); ACOMP(10, bA0, bA1, bA2, bA3);
    BAR();                                         WAITV(0); ACOMP(11, bB0, bB1, bB2, bB3);

    // epilogue: x write + fused ssq (wave owns cols [wave*32, wave*32+32), all 32 rows)
#pragma unroll
    for (int mt = 0; mt < 2; mt++) {
        int base = growbase + mt * 16;
        int bk0, bk1, b1start;
        if (base < QROWS)              { bk0 = base / 35;  bk1 = (base + 15) / 35;
                                         b1start = bk1 * 35; }
        else if (base < QROWS + PROWS) { int r0e = base - QROWS;
                                         bk0 = 96 + r0e / 180;  bk1 = 96 + (r0e + 15) / 180;
                                         b1start = QROWS + (bk1 - 96) * 180; }
        else                           { int r0e = base - QROWS - PROWS;
                                         bk0 = 192 + r0e / 180; bk1 = 192 + (r0e + 15) / 180;
                                         b1start = QROWS + PROWS + (bk1 - 192) * 180; }
#pragma unroll
        for (int ntl = 0; ntl < 2; ntl++) {
            int col = (wave * 2 + ntl) * 16 + m;
            float bv = bias[col];
            f32x4 s4 = acc[mt][ntl];
            float slo = 0.f, shi = 0.f;
#pragma unroll
            for (int r = 0; r < 4; r++) {
                int grow = base + quad * 4 + r;
                float v = s4[r] + bv;
                x[(size_t)grow * D_ + col] = v;
                float v2 = v * v;
                if (bk1 > bk0 && grow >= b1start) shi += v2; else slo += v2;
            }
            slo += __shfl_xor(slo, 16); slo += __shfl_xor(slo, 32);
            if (quad == 0) atomicAdd(ssq + (size_t)bk0 * D_ + col, slo);
            if (bk1 > bk0) {
                shi += __shfl_xor(shi, 16); shi += __shfl_xor(shi, 32);
                if (quad == 0) atomicAdd(ssq + (size_t)bk1 * D_ + col, shi);
            }
        }
    }
}

// ---------------- scale + bf16 + scatter: one thread per 16B frag chunk -----------------
__global__ __launch_bounds__(256) void scatter_k(
    const float* __restrict__ x, const float* __restrict__ ssq,
    const unsigned char* __restrict__ maskc,
    unsigned short* __restrict__ qfrag, unsigned short* __restrict__ pfrag) {
    int c = blockIdx.x * 256 + threadIdx.x;          // 651264 total = 2544*256
    int lane = c & 63, ks = (c >> 6) & 3;
    int quad = lane >> 4, mm = lane & 15;
    int d0 = ks * 32 + quad * 8;
    if (c < 61440) {
        int g = c >> 8;                              // qp*5 + mt
        int mt = g % 5, qp = g / 5;
        int prow = mt * 16 + mm;
        s16x8 outv = (s16x8){0, 0, 0, 0, 0, 0, 0, 0};
        if (prow < 70) {
            int hi = prow >= 35;
            int bq = qp * 2 + hi;
            int l = prow - hi * 35;
            size_t row = (size_t)bq * 35 + l;
            const f32x4* px = (const f32x4*)(x + row * D_ + d0);
            f32x4 v0 = px[0], v1 = px[1];
            const f32x4* pq = (const f32x4*)(ssq + (size_t)bq * D_ + d0);
            f32x4 q0 = pq[0], q1 = pq[1];
            f32x4 r0, r1;
#pragma unroll
            for (int j = 0; j < 4; j++) {
                r0[j] = rsqrtf(fmaxf(q0[j], 1e-24f));
                r1[j] = rsqrtf(fmaxf(q1[j], 1e-24f));
            }
            outv = pack_bf16(v0 * r0, v1 * r1);
        }
        *(s16x8*)(qfrag + (size_t)c * 8) = outv;
    } else {
        int c2 = c - 61440;
        int g = c2 >> 8;                             // pbk*12 + nt
        int nt = g % 12, pbk = g / 12;
        int l = nt * 16 + mm;
        int lsrc = (l < LP && maskc[pbk * LP + l]) ? l : 0;
        size_t row = QROWS + (size_t)pbk * LP + lsrc;
        const f32x4* px = (const f32x4*)(x + row * D_ + d0);
        f32x4 v0 = px[0], v1 = px[1];
        const f32x4* pq = (const f32x4*)(ssq + (size_t)(96 + pbk) * D_ + d0);
        f32x4 q0 = pq[0], q1 = pq[1];
        f32x4 r0, r1;
#pragma unroll
        for (int j = 0; j < 4; j++) {
            r0[j] = rsqrtf(fmaxf(q0[j], 1e-24f));
            r1[j] = rsqrtf(fmaxf(q1[j], 1e-24f));
        }
        *(s16x8*)(pfrag + (size_t)c2 * 8) = pack_bf16(v0 * r0, v1 * r1);
    }
}

// ---------------- late interaction: p-block staged via glds, XCD-pinned, mask-free ------
__global__ __launch_bounds__(256, 3) void interact_k(
    const unsigned short* __restrict__ qfrag, const unsigned short* __restrict__ pfrag,
    float* __restrict__ out) {
    __shared__ unsigned short plds[24576];           // 48 KB, shared by all 4 waves
    int wave = threadIdx.x >> 6, lane = threadIdx.x & 63;
    int b = blockIdx.x;                              // 2304 blocks
    int xcd = b & 7, i = b >> 3;                     // i in [0,288)
    int c = xcd * 24 + (i % 24);                     // [0,192)
    int qg = i / 24;                                 // [0,12)
    int side = c / 96, pb = c - side * 96;
    int qp = qg * 4 + wave;
    int m = lane & 15, quad = lane >> 4;

    const unsigned short* pbase = pfrag + (size_t)c * 24576;
    const unsigned short* qbase = qfrag + (size_t)qp * 10240;

#pragma unroll
    for (int ntl = 0; ntl < 3; ntl++) {
        int nt = wave * 3 + ntl;
#pragma unroll
        for (int ks = 0; ks < 4; ks++)
            glds16(pbase + ((size_t)(nt * 4 + ks) * 64 + lane) * 8,
                   &plds[(size_t)(nt * 4 + ks) * 512]);
    }

    s16x8 a[5][4];
#pragma unroll
    for (int mt = 0; mt < 5; mt++)
#pragma unroll
        for (int ks = 0; ks < 4; ks++)
            a[mt][ks] = *(const s16x8*)(qbase + ((size_t)(mt * 4 + ks) * 64 + lane) * 8);

    __syncthreads();                                 // drain staging

    const f32x4 zero4 = (f32x4){0.f, 0.f, 0.f, 0.f};
    float rmax[5][4];
#pragma unroll
    for (int mt = 0; mt < 5; mt++)
#pragma unroll
        for (int rr = 0; rr < 4; rr++) rmax[mt][rr] = NEGF;

    for (int nt = 0; nt < 12; nt++) {
        s16x8 bfr[4];
#pragma unroll
        for (int ks = 0; ks < 4; ks++)
            bfr[ks] = *(const s16x8*)&plds[((size_t)(nt * 4 + ks) * 64 + lane) * 8];
#pragma unroll
        for (int mt = 0; mt < 5; mt++) {
            f32x4 acc = __builtin_amdgcn_mfma_f32_16x16x32_bf16(a[mt][0], bfr[0], zero4, 0, 0, 0);
            acc = __builtin_amdgcn_mfma_f32_16x16x32_bf16(a[mt][1], bfr[1], acc, 0, 0, 0);
            acc = __builtin_amdgcn_mfma_f32_16x16x32_bf16(a[mt][2], bfr[2], acc, 0, 0, 0);
            acc = __builtin_amdgcn_mfma_f32_16x16x32_bf16(a[mt][3], bfr[3], acc, 0, 0, 0);
#pragma unroll
            for (int rr = 0; rr < 4; rr++)
                rmax[mt][rr] = fmaxf(rmax[mt][rr], acc[rr]);
        }
    }

#pragma unroll
    for (int mt = 0; mt < 5; mt++)
#pragma unroll
        for (int rr = 0; rr < 4; rr++) {
            float v = rmax[mt][rr];
            v = fmaxf(v, __shfl_xor(v, 1));
            v = fmaxf(v, __shfl_xor(v, 2));
            v = fmaxf(v, __shfl_xor(v, 4));
            v = fmaxf(v, __shfl_xor(v, 8));
            rmax[mt][rr] = v;
        }
    float s0 = 0.f, s1 = 0.f;
#pragma unroll
    for (int mt = 0; mt < 5; mt++)
#pragma unroll
        for (int rr = 0; rr < 4; rr++) {
            int prow = mt * 16 + quad * 4 + rr;
            float v = rmax[mt][rr];
            if (prow < 35) s0 += v;
            else if (prow < 70) s1 += v;
        }
    s0 += __shfl_xor(s0, 16); s0 += __shfl_xor(s0, 32);
    s1 += __shfl_xor(s1, 16); s1 += __shfl_xor(s1, 32);
    if (lane == 0) {
        int qb0 = qp * 2, qb1 = qp * 2 + 1;
        out[(size_t)qb0 * (2 * B_) + side * B_ + pb] = s0;
        out[(size_t)qb1 * (2 * B_) + side * B_ + pb] = s1;
    }
}

// ---------------- launch ----------------
extern "C" void kernel_launch(void* const* d_in, const int* in_sizes, int n_in,
                              void* d_out, int out_size, void* d_ws, size_t ws_size,
                              hipStream_t stream) {
    const float* qh   = (const float*)d_in[0];
    const float* ph   = (const float*)d_in[1];
    const float* nh   = (const float*)d_in[2];
    const float* W    = (const float*)d_in[3];
    const float* bias = (const float*)d_in[4];
    const void* pmask = d_in[5];
    const void* nmask = d_in[6];
    float* out = (float*)d_out;
    char* ws = (char*)d_ws;

    constexpr size_t CTRL_OFF  = 0;                          // 256 B
    constexpr size_t WTHI_OFF  = 256;                        // 196608 B
    constexpr size_t MASKC_OFF = WTHI_OFF + 196608;          // 34560 B -> ends 231424
    constexpr size_t SSQ_OFF   = 231424;                     // 147456 B
    constexpr size_t X_OFF     = SSQ_OFF + 147456;           // 19415040 B
    constexpr size_t QFRAG_OFF = X_OFF + (size_t)NROWS * D_ * 4;   // 983040 B
    constexpr size_t PFRAG_OFF = QFRAG_OFF + 983040;         // 9437184 B

    unsigned int* ctrl     = (unsigned int*)(ws + CTRL_OFF);
    unsigned short* wthi   = (unsigned short*)(ws + WTHI_OFF);
    unsigned char* maskc   = (unsigned char*)(ws + MASKC_OFF);
    float* ssq             = (float*)(ws + SSQ_OFF);
    float* x               = (float*)(ws + X_OFF);
    unsigned short* qfrag  = (unsigned short*)(ws + QFRAG_OFF);
    unsigned short* pfrag  = (unsigned short*)(ws + PFRAG_OFF);

    prep_k<<<193, 256, 0, stream>>>(W, wthi, (const unsigned int*)pmask, ctrl, ssq);
    proj_k<<<1185 + 135, 256, 0, stream>>>(qh, ph, nh, wthi, bias, x, ssq,
                                           pmask, nmask, ctrl, maskc);
    scatter_k<<<2544, 256, 0, stream>>>(x, ssq, maskc, qfrag, pfrag);
    interact_k<<<2304, 256, 0, stream>>>(qfrag, pfrag, out);
}